// Round 1
// baseline (134.646 us; speedup 1.0000x reference)
//
#include <hip/hip_runtime.h>
#include <math.h>

#define EEG_CH 64
#define WIN    128
#define NROWS  66
#define KW     9
#define OUTW   120   // 128 - 9 + 1
#define NOUT   10
#define NH     2

__launch_bounds__(1024)
__global__ void cnn_fused(const float* __restrict__ xg,
                          const float* __restrict__ w1g, const float* __restrict__ b1g,
                          const float* __restrict__ w2g, const float* __restrict__ b2g,
                          const float* __restrict__ cwg, const float* __restrict__ cbg,
                          const float* __restrict__ f1w, const float* __restrict__ f1b,
                          const float* __restrict__ f2w, const float* __restrict__ f2b,
                          float* __restrict__ out)
{
    __shared__ float xl[NROWS * WIN];          // 8448 floats = 33 KB
    __shared__ float rnorm[NROWS];             // per-row L2 norms of x rows
    __shared__ float nums[2];                  // dot(eeg[0], wav_a), dot(eeg[0], wav_b)
    __shared__ float eeg_r_l[128];             // (2,64) cosine features
    __shared__ float hl[128];                  // tanh hidden
    __shared__ float se_flat[128];             // softmax(sigmoid(...)) scales
    __shared__ float convout[NOUT * NH * OUTW];// 2400 relu'd conv outputs
    __shared__ float msum[NOUT * NH];          // mean over w

    const int tid  = threadIdx.x;
    const int ws   = tid >> 6;
    const int lane = tid & 63;

    // ---- Phase A: stage x into LDS ----
    for (int i = tid; i < NROWS * WIN; i += 1024) xl[i] = xg[i];
    __syncthreads();

    // ---- Phase B: row norms (66 rows) + the two scalar numerators ----
    for (int row = ws; row < NROWS; row += 16) {
        float v0 = xl[row * WIN + lane];
        float v1 = xl[row * WIN + 64 + lane];
        float s  = v0 * v0 + v1 * v1;
        for (int off = 32; off > 0; off >>= 1) s += __shfl_xor(s, off, 64);
        if (lane == 0) rnorm[row] = sqrtf(s);
    }
    if (ws < 2) {
        // num = dot(x row 1 (= eeg row 0), wav row)  where wav row = 0 (a) or 65 (b)
        const int wrow = (ws == 0) ? 0 : 65;
        float p = xl[WIN + lane]      * xl[wrow * WIN + lane]
                + xl[WIN + 64 + lane] * xl[wrow * WIN + 64 + lane];
        for (int off = 32; off > 0; off >>= 1) p += __shfl_xor(p, off, 64);
        if (lane == 0) nums[ws] = p;
    }
    __syncthreads();

    // ---- Phase C: eeg_r[r][i] = nums[r] / (||eeg row i|| * ||wav_r||) ----
    if (tid < 128) {
        const int r = tid >> 6, i = tid & 63;
        const float denom = rnorm[i + 1] * (r == 0 ? rnorm[0] : rnorm[65]);
        eeg_r_l[tid] = nums[r] / denom;
    }
    __syncthreads();

    // ---- Phase D: h = tanh(eeg_r @ se_w1^T + se_b1) ----
    if (tid < 128) {
        const int r = tid >> 6, j = tid & 63;
        float acc = b1g[j];
        #pragma unroll 8
        for (int i = 0; i < 64; ++i) acc += eeg_r_l[r * 64 + i] * w1g[j * 64 + i];
        hl[tid] = tanhf(acc);
    }
    __syncthreads();

    // ---- Phase E: se = softmax(sigmoid(h @ se_w2^T + se_b2), axis=1) ----
    if (tid < 128) {
        const int r = tid >> 6, j = tid & 63;
        float acc = b2g[j];
        #pragma unroll 8
        for (int i = 0; i < 64; ++i) acc += hl[r * 64 + i] * w2g[j * 64 + i];
        float sg = 1.0f / (1.0f + expf(-acc));
        // softmax across the 64 lanes of this wave (row r == wave r)
        float mx = sg;
        for (int off = 32; off > 0; off >>= 1) mx = fmaxf(mx, __shfl_xor(mx, off, 64));
        float e = expf(sg - mx);
        float ss = e;
        for (int off = 32; off > 0; off >>= 1) ss += __shfl_xor(ss, off, 64);
        se_flat[tid] = e / ss;
    }
    __syncthreads();

    // ---- Phase F: conv (10,1,64,9), stride (64,1), relu ----
    // out[o][h][w] = relu( b[o] + sum_i se[h*64+i] * sum_k eeg[i][w+k]*cw[o][i][k] )
    for (int idx = tid; idx < NOUT * NH * OUTW; idx += 1024) {
        const int o   = idx / (NH * OUTW);
        const int rem = idx - o * (NH * OUTW);
        const int h   = rem / OUTW;
        const int w   = rem - h * OUTW;
        float acc = cbg[o];
        const float* cwo = cwg + o * EEG_CH * KW;
        for (int i = 0; i < EEG_CH; ++i) {
            const float s = se_flat[h * 64 + i];
            const float* xrow = xl + (i + 1) * WIN + w;
            const float* cwr  = cwo + i * KW;
            float p = 0.f;
            #pragma unroll
            for (int k = 0; k < KW; ++k) p += xrow[k] * cwr[k];
            acc += s * p;
        }
        convout[idx] = fmaxf(acc, 0.f);
    }
    __syncthreads();

    // ---- Phase F2: mean over w (deterministic, 20 lanes) ----
    if (tid < NOUT * NH) {
        float s = 0.f;
        const float* co = convout + tid * OUTW;
        for (int w = 0; w < OUTW; ++w) s += co[w];
        msum[tid] = s * (1.0f / OUTW);
    }
    __syncthreads();

    // ---- Phase G: FCN 20 -> 10 -> 2 + softmax (thread 0) ----
    if (tid == 0) {
        float h2[10];
        for (int j = 0; j < 10; ++j) {
            float a = f1b[j];
            for (int p = 0; p < 20; ++p) a += msum[p] * f1w[j * 20 + p];
            h2[j] = 1.0f / (1.0f + expf(-a));
        }
        float l0 = f2b[0], l1 = f2b[1];
        for (int j = 0; j < 10; ++j) {
            l0 += h2[j] * f2w[j];
            l1 += h2[j] * f2w[10 + j];
        }
        const float m  = fmaxf(l0, l1);
        const float e0 = expf(l0 - m), e1 = expf(l1 - m);
        out[0] = e0 / (e0 + e1);
        out[1] = e1 / (e0 + e1);
    }
}

extern "C" void kernel_launch(void* const* d_in, const int* in_sizes, int n_in,
                              void* d_out, int out_size, void* d_ws, size_t ws_size,
                              hipStream_t stream) {
    (void)in_sizes; (void)n_in; (void)d_ws; (void)ws_size; (void)out_size;
    const float* xg  = (const float*)d_in[0];
    const float* w1  = (const float*)d_in[1];
    const float* b1  = (const float*)d_in[2];
    const float* w2  = (const float*)d_in[3];
    const float* b2  = (const float*)d_in[4];
    const float* cw  = (const float*)d_in[5];
    const float* cb  = (const float*)d_in[6];
    const float* f1w = (const float*)d_in[7];
    const float* f1b = (const float*)d_in[8];
    const float* f2w = (const float*)d_in[9];
    const float* f2b = (const float*)d_in[10];
    float* out = (float*)d_out;
    cnn_fused<<<dim3(1), dim3(1024), 0, stream>>>(xg, w1, b1, w2, b2, cw, cb,
                                                  f1w, f1b, f2w, f2b, out);
}

// Round 2
// 94.555 us; speedup vs baseline: 1.4240x; 1.4240x over previous
//
#include <hip/hip_runtime.h>
#include <math.h>

#define EEG_CH 64
#define WIN    128
#define ROWP   132          // padded row stride (floats), keeps float2 reads 8B-aligned
#define NROWS  66
#define KW     9
#define OUTW   120          // 128 - 9 + 1
#define NOUT   10
#define NH     2

__launch_bounds__(1024)
__global__ void cnn_fused(const float* __restrict__ xg,
                          const float* __restrict__ w1g, const float* __restrict__ b1g,
                          const float* __restrict__ w2g, const float* __restrict__ b2g,
                          const float* __restrict__ cwg, const float* __restrict__ cbg,
                          const float* __restrict__ f1w, const float* __restrict__ f1b,
                          const float* __restrict__ f2w, const float* __restrict__ f2b,
                          float* __restrict__ out)
{
    __shared__ float xl[NROWS * ROWP];   // 66*132*4 = 34.8 KB
    __shared__ float rnorm[NROWS];
    __shared__ float nums[2];
    __shared__ float eeg_r_l[128];       // (2,64)
    __shared__ float hl[128];
    __shared__ float se_flat[128];
    __shared__ float msum[NOUT * NH];    // [o][h] means
    __shared__ float h2l[16];

    const int tid  = threadIdx.x;
    const int ws   = tid >> 6;
    const int lane = tid & 63;

    // ---- Phase A: stage x into LDS (row-padded), float4 both sides ----
    // 66 rows * 32 float4 = 2112 tasks
    for (int t = tid; t < NROWS * (WIN / 4); t += 1024) {
        const int row = t >> 5, c4 = t & 31;
        const float4 v = *(const float4*)(xg + row * WIN + c4 * 4);
        *(float4*)(xl + row * ROWP + c4 * 4) = v;
    }
    __syncthreads();

    // ---- Phase B: row norms + the two scalar numerators ----
    for (int row = ws; row < NROWS; row += 16) {
        float v0 = xl[row * ROWP + lane];
        float v1 = xl[row * ROWP + 64 + lane];
        float s  = v0 * v0 + v1 * v1;
        for (int off = 32; off > 0; off >>= 1) s += __shfl_xor(s, off, 64);
        if (lane == 0) rnorm[row] = sqrtf(s);
    }
    if (ws < 2) {
        const int wrow = (ws == 0) ? 0 : 65;
        float p = xl[ROWP + lane]      * xl[wrow * ROWP + lane]
                + xl[ROWP + 64 + lane] * xl[wrow * ROWP + 64 + lane];
        for (int off = 32; off > 0; off >>= 1) p += __shfl_xor(p, off, 64);
        if (lane == 0) nums[ws] = p;
    }
    __syncthreads();

    // ---- Phases C/D/E: 2 waves (r = ws), intra-wave LDS deps only ----
    if (ws < 2) {
        const int r = ws, j = lane;
        // C: cosine features
        {
            const float denom = rnorm[j + 1] * (r == 0 ? rnorm[0] : rnorm[65]);
            eeg_r_l[r * 64 + j] = nums[r] / denom;
        }
        // D: h = tanh(eeg_r @ w1^T + b1), float4 dot
        {
            float acc = b1g[j];
            const float4* wr = (const float4*)(w1g + j * 64);
            const float4* er = (const float4*)(eeg_r_l + r * 64);
            #pragma unroll
            for (int i = 0; i < 16; ++i) {
                const float4 a = er[i], b = wr[i];
                acc += a.x * b.x + a.y * b.y + a.z * b.z + a.w * b.w;
            }
            hl[r * 64 + j] = tanhf(acc);
        }
        // E: se = softmax(sigmoid(h @ w2^T + b2), axis=1)
        {
            float acc = b2g[j];
            const float4* wr = (const float4*)(w2g + j * 64);
            const float4* hr = (const float4*)(hl + r * 64);
            #pragma unroll
            for (int i = 0; i < 16; ++i) {
                const float4 a = hr[i], b = wr[i];
                acc += a.x * b.x + a.y * b.y + a.z * b.z + a.w * b.w;
            }
            float sg = 1.0f / (1.0f + expf(-acc));
            float mx = sg;
            for (int off = 32; off > 0; off >>= 1) mx = fmaxf(mx, __shfl_xor(mx, off, 64));
            float e = expf(sg - mx);
            float ss = e;
            for (int off = 32; off > 0; off >>= 1) ss += __shfl_xor(ss, off, 64);
            se_flat[r * 64 + j] = e / ss;
        }
    }
    __syncthreads();

    // ---- Phase F: conv + relu + mean, one wave per output channel o ----
    // out[o][h][w] = relu(b[o] + sum_i se[h*64+i] * p_i(w)),
    // p_i(w) = sum_k x[i+1][w+k]*cw[o][i][k]; p shared across h.
    const int wu = __builtin_amdgcn_readfirstlane(ws);   // wave-uniform wave id
    if (wu < NOUT) {
        const int o = wu;
        const float* __restrict__ cwo = cwg + o * EEG_CH * KW;  // uniform -> s_load
        const int wbase = (lane < 60) ? 2 * lane : 116;         // lanes 60-63 redundant
        float a00 = 0.f, a01 = 0.f, a10 = 0.f, a11 = 0.f;       // [h][w0/w1]

        #pragma unroll 4
        for (int i = 0; i < EEG_CH; ++i) {
            // 10-float window [wbase .. wbase+9] via 5 aligned float2 LDS reads
            const float2* xp = (const float2*)(xl + (i + 1) * ROWP + wbase);
            const float2 x0 = xp[0], x1 = xp[1], x2 = xp[2], x3 = xp[3], x4 = xp[4];
            const float xw[10] = { x0.x, x0.y, x1.x, x1.y, x2.x, x2.y,
                                   x3.x, x3.y, x4.x, x4.y };
            // wave-uniform weights (scalar loads) and se broadcasts
            float wk[KW];
            #pragma unroll
            for (int k = 0; k < KW; ++k) wk[k] = cwo[i * KW + k];
            const float s0 = se_flat[i];
            const float s1 = se_flat[64 + i];

            float p0 = 0.f, p1 = 0.f;
            #pragma unroll
            for (int k = 0; k < KW; ++k) {
                p0 += xw[k]     * wk[k];
                p1 += xw[k + 1] * wk[k];
            }
            a00 += s0 * p0;  a01 += s0 * p1;
            a10 += s1 * p0;  a11 += s1 * p1;
        }

        const float bo = cbg[o];
        float r0 = fmaxf(a00 + bo, 0.f) + fmaxf(a01 + bo, 0.f);  // h=0
        float r1 = fmaxf(a10 + bo, 0.f) + fmaxf(a11 + bo, 0.f);  // h=1
        if (lane >= 60) { r0 = 0.f; r1 = 0.f; }
        for (int off = 32; off > 0; off >>= 1) {
            r0 += __shfl_xor(r0, off, 64);
            r1 += __shfl_xor(r1, off, 64);
        }
        if (lane == 0) {
            msum[o * NH + 0] = r0 * (1.0f / OUTW);
            msum[o * NH + 1] = r1 * (1.0f / OUTW);
        }
    }
    __syncthreads();

    // ---- Phase G: FCN 20 -> 10 -> 2 + softmax, wave 0 ----
    if (ws == 0) {
        float h2v = 0.f;
        if (lane < 10) {
            float a = f1b[lane];
            #pragma unroll
            for (int p = 0; p < 20; ++p) a += msum[p] * f1w[lane * 20 + p];
            h2v = 1.0f / (1.0f + expf(-a));
        }
        h2l[lane & 15] = 0.f;              // zero pad (only lanes 0..15 slots used)
        if (lane < 10) h2l[lane] = h2v;
        // intra-wave LDS write->read is ordered; no barrier needed
        float t0 = (lane < 10) ? h2v * f2w[lane]      : 0.f;
        float t1 = (lane < 10) ? h2v * f2w[10 + lane] : 0.f;
        for (int off = 32; off > 0; off >>= 1) {
            t0 += __shfl_xor(t0, off, 64);
            t1 += __shfl_xor(t1, off, 64);
        }
        if (lane == 0) {
            const float l0 = f2b[0] + t0, l1 = f2b[1] + t1;
            const float m  = fmaxf(l0, l1);
            const float e0 = expf(l0 - m), e1 = expf(l1 - m);
            out[0] = e0 / (e0 + e1);
            out[1] = e1 / (e0 + e1);
        }
    }
}

extern "C" void kernel_launch(void* const* d_in, const int* in_sizes, int n_in,
                              void* d_out, int out_size, void* d_ws, size_t ws_size,
                              hipStream_t stream) {
    (void)in_sizes; (void)n_in; (void)d_ws; (void)ws_size; (void)out_size;
    const float* xg  = (const float*)d_in[0];
    const float* w1  = (const float*)d_in[1];
    const float* b1  = (const float*)d_in[2];
    const float* w2  = (const float*)d_in[3];
    const float* b2  = (const float*)d_in[4];
    const float* cw  = (const float*)d_in[5];
    const float* cb  = (const float*)d_in[6];
    const float* f1w = (const float*)d_in[7];
    const float* f1b = (const float*)d_in[8];
    const float* f2w = (const float*)d_in[9];
    const float* f2b = (const float*)d_in[10];
    float* out = (float*)d_out;
    cnn_fused<<<dim3(1), dim3(1024), 0, stream>>>(xg, w1, b1, w2, b2, cw, cb,
                                                  f1w, f1b, f2w, f2b, out);
}